// Round 17
// baseline (36.275 us; speedup 1.0000x reference)
//
#include <hip/hip_runtime.h>
#include <math.h>

static constexpr int B_ = 32;
static constexpr int RES_ = 50;
#define NF (1.0f/(2.0f*0.05f*0.05f + 1e-8f))
#define QSCALE 2048.0f                      // u16 bin quantization
#define QINV   (1.0f / 2048.0f)
#define EX(x)  __builtin_amdgcn_exp2f(x)    // native v_exp_f32 (2^x)
#define SQ(x)  ((x)*(x))

// ---------------------------------------------------------------------------
// K0: quantize each point ONCE: pack = ix<<24 | iy<<16 | v, where ix,iy are
//     NN bins (0..255) and v = min(pers^2 * QSCALE, 65535). Removes the 8x
//     redundant per-point float math from the fused scan (23 -> ~9 inst/pt).
// ---------------------------------------------------------------------------
__device__ __forceinline__ unsigned packpt(float bx, float dy) {
    int ix = (int)(fminf(fmaxf(bx * 255.0f + 0.5f, 0.0f), 255.0f));
    int iy = (int)(fminf(fmaxf(dy * 255.0f + 0.5f, 0.0f), 255.0f));
    float pers = fminf(fabsf(dy - bx), 10.0f);
    unsigned v = (unsigned)(fminf(pers * pers * QSCALE, 65535.0f) + 0.5f);
    return ((unsigned)ix << 24) | ((unsigned)iy << 16) | v;
}

__global__ void __launch_bounds__(256) k_prep(const float4* __restrict__ pts,
                                              uint2* __restrict__ pk, int nq) {
    int stride = gridDim.x * 256;
    for (int t = blockIdx.x * 256 + threadIdx.x; t < nq; t += stride) {
        float4 q = pts[t];
        pk[t] = make_uint2(packpt(q.x, q.y), packpt(q.z, q.w));
    }
}

// ---------------------------------------------------------------------------
// K1: FUSED splat + both contractions, spatial partitioning (R15 structure).
//     Grid 256 = (part:8, b:32), id%8==b%8 (8 blocks/batch share one XCD's
//     L2 -> 256 KB packed points fetched from HBM once per batch). Block owns
//     the 128x64 region (xh = part&1, yo = part>>1); scans packed u32 points
//     (uint4 = 4 pts/load, ~9 inst/pt), 1 packed ds_add_u32 per in-region pt.
//     Stage1: cx-contraction vs Gaussian-x slot table (slot ig*8+k -> row
//     i=ig*7+k, k<7, i<50). Stage2: cy-contraction, inline-exp Gaussian-y.
//     partial[part*32+b][50][50]. LDS: tile 16KB | gx 32KB | tmpP 28KB = 76KB.
// ---------------------------------------------------------------------------
__global__ void __launch_bounds__(1024, 1) k_fused(const unsigned* __restrict__ pk,
                                                   float* __restrict__ partial) {
    extern __shared__ unsigned lds[];
    unsigned* tile = lds;                        // 4096 u32
    float* gx   = (float*)(lds + 4096);          // 8192 f32
    float* tmpP = (float*)(lds + 4096 + 8192);   // 7168 f32

    int id = blockIdx.x;
    int b    = id & 31;
    int part = id >> 5;                     // 0..7
    int xh = part & 1, yo = part >> 1;
    int tid = threadIdx.x;
    const float S2 = sqrtf(NF * 1.44269504f);   // const-folded

    // --- init: zero tile, build Gaussian-x slot table ---
    for (int t = tid; t < 4096; t += 1024) tile[t] = 0u;
    for (int t = tid; t < 8192; t += 1024) {
        int cxL = t >> 6, s = t & 63;
        int ig = s >> 3, k = s & 7;
        int i = ig * 7 + k;
        float v = 0.0f;
        if (k < 7 && i < RES_) {
            float d = ((float)i * (1.0f / 49.0f)
                     - (float)((xh << 7) + cxL) * (1.0f / 255.0f)) * S2;
            v = EX(-SQ(d));
        }
        gx[t] = v;
    }
    __syncthreads();

    // --- scan packed points + NN splat (region-filtered) ---
    const uint4* src = (const uint4*)(pk + ((size_t)b << 16));
    int xlo = xh << 7, ylo = yo << 6;
    for (int t = tid; t < 16384; t += 1024) {
        uint4 q = src[t];
#pragma unroll
        for (int e = 0; e < 4; e++) {
            unsigned u = e == 0 ? q.x : (e == 1 ? q.y : (e == 2 ? q.z : q.w));
            int lx = (int)(u >> 24) - xlo;
            int ly = (int)((u >> 16) & 255u) - ylo;
            if (((unsigned)lx < 128u) & ((unsigned)ly < 64u))
                atomicAdd(tile + (lx << 5) + (ly >> 1),
                          (u & 0xffffu) << ((ly & 1) << 4));
        }
    }
    __syncthreads();

    // --- stage1: tmp[i][cyL] = sum_cx gx[cx][i] * tile[cx][cyL] ---
    {
        int cyL = tid & 63;
        int ig  = (tid >> 6) & 7;           // wave-uniform
        int cxh = tid >> 9;                 // wave-uniform
        float acc[7];
#pragma unroll
        for (int k = 0; k < 7; k++) acc[k] = 0.0f;
#pragma unroll 4
        for (int c = 0; c < 64; c++) {
            int cx = (cxh << 6) + c;
            unsigned wrd = tile[(cx << 5) + (cyL >> 1)];
            float hv = (float)((wrd >> ((cyL & 1) << 4)) & 0xffffu) * QINV;
            const float* g = gx + (cx << 6) + (ig << 3);
            float4 g0 = *(const float4*)(g);
            float4 g1 = *(const float4*)(g + 4);
            acc[0] += g0.x * hv;  acc[1] += g0.y * hv;
            acc[2] += g0.z * hv;  acc[3] += g0.w * hv;
            acc[4] += g1.x * hv;  acc[5] += g1.y * hv;
            acc[6] += g1.z * hv;                 // slot 7 = zero pad
        }
        float* tp = tmpP + (size_t)cxh * 3584 + (ig * 7) * 64 + cyL;
#pragma unroll
        for (int k = 0; k < 7; k++) tp[k * 64] = acc[k];
    }
    __syncthreads();
    for (int t = tid; t < 3584; t += 1024) tmpP[t] += tmpP[t + 3584];
    __syncthreads();

    // --- stage2: out[i][j] = sum_cy tmp[i][cy] * gy[ylo+cy][j] ---
    {
        int j  = tid & 63;
        int iq = tid >> 6;                  // 0..15, use 0..13 (56 rows)
        if (iq < 14) {
            int jc = j < RES_ ? j : RES_ - 1;
            float xjS = (float)jc * (1.0f / 49.0f) * S2;
            float a0 = 0.f, a1 = 0.f, a2 = 0.f, a3 = 0.f;
            const float* tq = tmpP + (iq * 4) * 64;
#pragma unroll 4
            for (int c = 0; c < 64; c++) {
                float d = xjS - (float)(ylo + c) * (1.0f / 255.0f) * S2;
                float g = EX(-SQ(d));
                a0 += tq[c] * g;
                a1 += tq[64 + c] * g;
                a2 += tq[128 + c] * g;
                a3 += tq[192 + c] * g;
            }
            if (j < RES_) {
                float* dst = partial + (size_t)id * 2500;
                int i0 = iq * 4;
                if (i0 + 0 < RES_) dst[(i0 + 0) * RES_ + j] = a0;
                if (i0 + 1 < RES_) dst[(i0 + 1) * RES_ + j] = a1;
                if (i0 + 2 < RES_) dst[(i0 + 2) * RES_ + j] = a2;
                if (i0 + 3 < RES_) dst[(i0 + 3) * RES_ + j] = a3;
            }
        }
    }
}

// ---------------------------------------------------------------------------
// K2: out[b][f] = sum_{part<8} partial[part*32+b][f]
//     Grid 128 = (q:4, b:32), id%8==b%8 (partials XCD-local).
// ---------------------------------------------------------------------------
__global__ void __launch_bounds__(256) k_red(const float* __restrict__ partial,
                                             float* __restrict__ out) {
    int b  = blockIdx.x & 31;
    int qq = blockIdx.x >> 5;
    const float* p = partial + (size_t)b * 2500;
    int lo = qq * 625, hi = lo + 625;
    for (int f = lo + threadIdx.x; f < hi; f += 256) {
        float s = 0.0f;
#pragma unroll
        for (int k = 0; k < 8; k++) s += p[(size_t)k * 32 * 2500 + f];
        out[(size_t)b * 2500 + f] = s;
    }
}

// ---------------------------------------------------------------------------
extern "C" void kernel_launch(void* const* d_in, const int* in_sizes, int n_in,
                              void* d_out, int out_size, void* d_ws, size_t ws_size,
                              hipStream_t stream) {
    const float4* pts = (const float4*)d_in[0];
    unsigned* pk = (unsigned*)d_ws;          // 2,097,152 u32 = 8.4 MB
    float* partial = (float*)d_ws + (size_t)2 * 1024 * 1024;  // 2.56 MB
    float* out = (float*)d_out;

    hipFuncSetAttribute((const void*)k_fused,
                        hipFuncAttributeMaxDynamicSharedMemorySize, 77824);

    int nq = B_ * 32768;                     // 1,048,576 float4 (2 pts each)
    k_prep<<<2048, 256, 0, stream>>>(pts, (uint2*)pk, nq);
    k_fused<<<256, 1024, 77824, stream>>>(pk, partial);
    k_red<<<128, 256, 0, stream>>>(partial, out);
}

// Round 18
// 31.584 us; speedup vs baseline: 1.1485x; 1.1485x over previous
//
#include <hip/hip_runtime.h>
#include <math.h>

static constexpr int B_ = 32;
static constexpr int RES_ = 50;
static constexpr int CAP = 2048;            // per (hq,b,part) bucket capacity
#define NF (1.0f/(2.0f*0.05f*0.05f + 1e-8f))
#define QSCALE 2048.0f                      // u16 bin quantization
#define QINV   (1.0f / 2048.0f)
#define EX(x)  __builtin_amdgcn_exp2f(x)    // native v_exp_f32 (2^x)
#define SQ(x)  ((x)*(x))

// ---------------------------------------------------------------------------
// K0: pack each point ONCE (ix<<24 | iy<<16 | v) and BUCKET it by region
//     part = (iy>>6)*2 + (ix>>7), so the fused scan touches only its own
//     points with all 64 lanes active. Grid 256 = (hq:8, b:32), id%32==b;
//     each block handles 8192 points of batch b, reserving slots via native
//     LDS ds_add_rtn_u32 counters. Buckets padded to x4 with v=0 no-ops.
//     pkb[(hq*32+b)][part:8][slot:CAP] u32; cnt4 = padded count / 4.
// ---------------------------------------------------------------------------
__device__ __forceinline__ unsigned packpt(float bx, float dy) {
    int ix = (int)(fminf(fmaxf(bx * 255.0f + 0.5f, 0.0f), 255.0f));
    int iy = (int)(fminf(fmaxf(dy * 255.0f + 0.5f, 0.0f), 255.0f));
    float pers = fminf(fabsf(dy - bx), 10.0f);
    unsigned v = (unsigned)(fminf(pers * pers * QSCALE, 65535.0f) + 0.5f);
    return ((unsigned)ix << 24) | ((unsigned)iy << 16) | v;
}

__global__ void __launch_bounds__(1024) k_bucket(const float4* __restrict__ pts,
                                                 unsigned* __restrict__ pkb,
                                                 unsigned* __restrict__ cnt4) {
    __shared__ unsigned lcnt[8];
    int id = blockIdx.x;
    int b = id & 31, hq = id >> 5;          // hq 0..7
    int tid = threadIdx.x;
    if (tid < 8) lcnt[tid] = 0u;
    __syncthreads();

    const float4* src = pts + ((size_t)b << 15) + ((size_t)hq << 12);  // 4096 f4
    unsigned* mybase = pkb + ((size_t)id << 14);    // 8 * CAP u32 per block
    for (int t = tid; t < 4096; t += 1024) {
        float4 q = src[t];
#pragma unroll
        for (int h = 0; h < 2; h++) {
            float bx = h ? q.z : q.x;
            float dy = h ? q.w : q.y;
            unsigned u = packpt(bx, dy);
            int part = ((int)((u >> 22) & 3u) << 1) | (int)(u >> 31);
            unsigned slot = atomicAdd(&lcnt[part], 1u);
            if (slot < (unsigned)CAP) mybase[(part << 11) + slot] = u;
        }
    }
    __syncthreads();
    if (tid < 8) {
        unsigned base = lcnt[tid]; if (base > (unsigned)CAP) base = CAP;
        unsigned padded = (base + 3u) & ~3u; if (padded > (unsigned)CAP) padded = CAP;
        for (unsigned k = base; k < padded; k++) mybase[((unsigned)tid << 11) + k] = 0u;
        cnt4[(id << 3) + tid] = padded >> 2;
    }
}

// ---------------------------------------------------------------------------
// K1: FUSED splat + both contractions (R15/R17 structure, bucketed scan).
//     Grid 256 = (part:8, b:32), id%8==b%8. Block owns the 128x64 region
//     (xh=part&1, yo=part>>1); scans its 8 bucket segments (~8192 points,
//     uint4 loads, all lanes active) -> 1 packed ds_add_u32 per point.
//     Stage1: cx-contraction vs Gaussian-x slot table (slot ig*8+k -> row
//     i=ig*7+k, k<7, i<50). Stage2: cy-contraction, inline-exp Gaussian-y.
//     partial[part*32+b][50][50]. LDS: tile 16KB | gx 32KB | tmpP 28KB = 76KB.
// ---------------------------------------------------------------------------
__global__ void __launch_bounds__(1024, 1) k_fused(const unsigned* __restrict__ pkb,
                                                   const unsigned* __restrict__ cnt4,
                                                   float* __restrict__ partial) {
    extern __shared__ unsigned lds[];
    unsigned* tile = lds;                        // 4096 u32
    float* gx   = (float*)(lds + 4096);          // 8192 f32
    float* tmpP = (float*)(lds + 4096 + 8192);   // 7168 f32

    int id = blockIdx.x;
    int b    = id & 31;
    int part = id >> 5;                     // 0..7
    int xh = part & 1, yo = part >> 1;
    int tid = threadIdx.x;
    const float S2 = sqrtf(NF * 1.44269504f);   // const-folded

    // --- init: zero tile, build Gaussian-x slot table ---
    for (int t = tid; t < 4096; t += 1024) tile[t] = 0u;
    for (int t = tid; t < 8192; t += 1024) {
        int cxL = t >> 6, s = t & 63;
        int ig = s >> 3, k = s & 7;
        int i = ig * 7 + k;
        float v = 0.0f;
        if (k < 7 && i < RES_) {
            float d = ((float)i * (1.0f / 49.0f)
                     - (float)((xh << 7) + cxL) * (1.0f / 255.0f)) * S2;
            v = EX(-SQ(d));
        }
        gx[t] = v;
    }
    __syncthreads();

    // --- scan this region's 8 bucket segments + NN splat ---
    int xlo = xh << 7, ylo = yo << 6;
    for (int hq = 0; hq < 8; hq++) {
        int blk = (hq << 5) + b;
        int n4 = (int)cnt4[(blk << 3) + part];
        const uint4* src = (const uint4*)(pkb + ((size_t)blk << 14) + (part << 11));
        for (int t = tid; t < n4; t += 1024) {
            uint4 q = src[t];
#pragma unroll
            for (int e = 0; e < 4; e++) {
                unsigned u = e == 0 ? q.x : (e == 1 ? q.y : (e == 2 ? q.z : q.w));
                int lx = (int)(u >> 24) - xlo;
                int ly = (int)((u >> 16) & 255u) - ylo;
                if (((unsigned)lx < 128u) & ((unsigned)ly < 64u))
                    atomicAdd(tile + (lx << 5) + (ly >> 1),
                              (u & 0xffffu) << ((ly & 1) << 4));
            }
        }
    }
    __syncthreads();

    // --- stage1: tmp[i][cyL] = sum_cx gx[cx][i] * tile[cx][cyL] ---
    {
        int cyL = tid & 63;
        int ig  = (tid >> 6) & 7;           // wave-uniform
        int cxh = tid >> 9;                 // wave-uniform
        float acc[7];
#pragma unroll
        for (int k = 0; k < 7; k++) acc[k] = 0.0f;
#pragma unroll 4
        for (int c = 0; c < 64; c++) {
            int cx = (cxh << 6) + c;
            unsigned wrd = tile[(cx << 5) + (cyL >> 1)];
            float hv = (float)((wrd >> ((cyL & 1) << 4)) & 0xffffu) * QINV;
            const float* g = gx + (cx << 6) + (ig << 3);
            float4 g0 = *(const float4*)(g);
            float4 g1 = *(const float4*)(g + 4);
            acc[0] += g0.x * hv;  acc[1] += g0.y * hv;
            acc[2] += g0.z * hv;  acc[3] += g0.w * hv;
            acc[4] += g1.x * hv;  acc[5] += g1.y * hv;
            acc[6] += g1.z * hv;                 // slot 7 = zero pad
        }
        float* tp = tmpP + (size_t)cxh * 3584 + (ig * 7) * 64 + cyL;
#pragma unroll
        for (int k = 0; k < 7; k++) tp[k * 64] = acc[k];
    }
    __syncthreads();
    for (int t = tid; t < 3584; t += 1024) tmpP[t] += tmpP[t + 3584];
    __syncthreads();

    // --- stage2: out[i][j] = sum_cy tmp[i][cy] * gy[ylo+cy][j] ---
    {
        int j  = tid & 63;
        int iq = tid >> 6;                  // 0..15, use 0..13 (56 rows)
        if (iq < 14) {
            int jc = j < RES_ ? j : RES_ - 1;
            float xjS = (float)jc * (1.0f / 49.0f) * S2;
            float a0 = 0.f, a1 = 0.f, a2 = 0.f, a3 = 0.f;
            const float* tq = tmpP + (iq * 4) * 64;
#pragma unroll 4
            for (int c = 0; c < 64; c++) {
                float d = xjS - (float)(ylo + c) * (1.0f / 255.0f) * S2;
                float g = EX(-SQ(d));
                a0 += tq[c] * g;
                a1 += tq[64 + c] * g;
                a2 += tq[128 + c] * g;
                a3 += tq[192 + c] * g;
            }
            if (j < RES_) {
                float* dst = partial + (size_t)id * 2500;
                int i0 = iq * 4;
                if (i0 + 0 < RES_) dst[(i0 + 0) * RES_ + j] = a0;
                if (i0 + 1 < RES_) dst[(i0 + 1) * RES_ + j] = a1;
                if (i0 + 2 < RES_) dst[(i0 + 2) * RES_ + j] = a2;
                if (i0 + 3 < RES_) dst[(i0 + 3) * RES_ + j] = a3;
            }
        }
    }
}

// ---------------------------------------------------------------------------
// K2: out[b][f] = sum_{part<8} partial[part*32+b][f]
//     Grid 128 = (q:4, b:32), id%8==b%8 (partials XCD-local).
// ---------------------------------------------------------------------------
__global__ void __launch_bounds__(256) k_red(const float* __restrict__ partial,
                                             float* __restrict__ out) {
    int b  = blockIdx.x & 31;
    int qq = blockIdx.x >> 5;
    const float* p = partial + (size_t)b * 2500;
    int lo = qq * 625, hi = lo + 625;
    for (int f = lo + threadIdx.x; f < hi; f += 256) {
        float s = 0.0f;
#pragma unroll
        for (int k = 0; k < 8; k++) s += p[(size_t)k * 32 * 2500 + f];
        out[(size_t)b * 2500 + f] = s;
    }
}

// ---------------------------------------------------------------------------
extern "C" void kernel_launch(void* const* d_in, const int* in_sizes, int n_in,
                              void* d_out, int out_size, void* d_ws, size_t ws_size,
                              hipStream_t stream) {
    const float4* pts = (const float4*)d_in[0];
    unsigned* pkb  = (unsigned*)d_ws;                      // 256*16384 u32 = 16.8 MB
    unsigned* cnt4 = pkb + (size_t)256 * 16384;            // 2048 u32
    float* partial = (float*)(cnt4 + 2048);                // 256*2500 f32 = 2.56 MB
    float* out = (float*)d_out;

    hipFuncSetAttribute((const void*)k_fused,
                        hipFuncAttributeMaxDynamicSharedMemorySize, 77824);

    k_bucket<<<256, 1024, 0, stream>>>(pts, pkb, cnt4);
    k_fused<<<256, 1024, 77824, stream>>>(pkb, cnt4, partial);
    k_red<<<128, 256, 0, stream>>>(partial, out);
}